// Round 11
// baseline (134.136 us; speedup 1.0000x reference)
//
#include <hip/hip_runtime.h>
#include <hip/hip_bf16.h>
#include <stdint.h>

typedef __bf16 bf16x8 __attribute__((ext_vector_type(8)));
typedef float  f32x4  __attribute__((ext_vector_type(4)));

static constexpr int Mdim = 2048;   // B*S
static constexpr int Ndim = 4096;   // O
static constexpr int Kdim = 4096;   // I = G*A
static constexpr int NT   = 64;     // K-tiles (BK=64)
static constexpr int WPK_BLOCKS = 8192;   // 32768 packs / 4 waves per block
static constexpr int CVT_BLOCKS = (Mdim * Kdim / 8) / 256;   // 4096

// ---------------- prep: dequant W -> PACKED fragment layout (bf16), cast X.
// Pack p = ((((tn*64+t)*4+wn)*4+nf)*2+h); slot lane l within pack holds
// W[o = tn*256+wn*64+nf*16+(l&15)][k0 = t*64 + h*32 + (l>>4)*8 .. +7]
// -> exactly the per-lane B-fragment of mfma_f32_16x16x32_bf16.
__global__ __launch_bounds__(256)
void prep(const float* __restrict__ binary, const float* __restrict__ alpha,
          const float* __restrict__ x, __bf16* __restrict__ wp,
          __bf16* __restrict__ xb) {
  const int b = blockIdx.x;
  const int t = threadIdx.x;
  if (b < WPK_BLOCKS) {
    const int pack = b * 4 + (t >> 6);
    const int lane = t & 63;
    const int h  = pack & 1;
    const int nf = (pack >> 1) & 3;
    const int wn = (pack >> 3) & 3;
    const int tt = (pack >> 5) & 63;
    const int tn = pack >> 11;
    const int o  = tn * 256 + wn * 64 + nf * 16 + (lane & 15);
    const int k0 = tt * 64 + h * 32 + (lane >> 4) * 8;
    const float* al = alpha + ((long)o * 32 + (k0 >> 7)) * 3;
    float a0 = al[0], a1 = al[1], a2 = al[2];
    const float4* q = (const float4*)(binary + ((long)o * Kdim + k0) * 3);  // 96B
    float4 q0 = q[0], q1 = q[1], q2 = q[2], q3 = q[3], q4 = q[4], q5 = q[5];
    bf16x8 wv;
    wv[0] = (__bf16)(a0 * q0.x + a1 * q0.y + a2 * q0.z);
    wv[1] = (__bf16)(a0 * q0.w + a1 * q1.x + a2 * q1.y);
    wv[2] = (__bf16)(a0 * q1.z + a1 * q1.w + a2 * q2.x);
    wv[3] = (__bf16)(a0 * q2.y + a1 * q2.z + a2 * q2.w);
    wv[4] = (__bf16)(a0 * q3.x + a1 * q3.y + a2 * q3.z);
    wv[5] = (__bf16)(a0 * q3.w + a1 * q4.x + a2 * q4.y);
    wv[6] = (__bf16)(a0 * q4.z + a1 * q4.w + a2 * q5.x);
    wv[7] = (__bf16)(a0 * q5.y + a1 * q5.z + a2 * q5.w);
    *(bf16x8*)(wp + (long)pack * 512 + lane * 8) = wv;   // wave = 1KB contiguous
  } else {
    long e = ((long)(b - WPK_BLOCKS) * 256 + t) * 8;
    float4 v0 = *(const float4*)(x + e);
    float4 v1 = *(const float4*)(x + e + 4);
    bf16x8 r;
    r[0] = (__bf16)v0.x; r[1] = (__bf16)v0.y; r[2] = (__bf16)v0.z; r[3] = (__bf16)v0.w;
    r[4] = (__bf16)v1.x; r[5] = (__bf16)v1.y; r[6] = (__bf16)v1.z; r[7] = (__bf16)v1.w;
    *(bf16x8*)(xb + e) = r;
  }
}

// ---------------- GEMM: 128x256 tile, 8 waves (2Mx4N), wave 64x64, BK=64.
// A via LDS (3-buf, XOR-swizzled); B reg-direct from packed W (no LDS).
// 1 barrier/K-tile; vmcnt ledger: per tile issue {B(t+1)=8, stageA(t+2)=2},
// GATE(2) at tile entry retires A(t)+B(t); prologue A0,B0,A1; last tile GATE(0).
__device__ __forceinline__ void g2l16(const void* g, void* l) {
  __builtin_amdgcn_global_load_lds(
      (const __attribute__((address_space(1))) void*)g,
      (__attribute__((address_space(3))) void*)l, 16, 0, 0);
}

#define BAR()    __builtin_amdgcn_s_barrier()
#define LGKM0()  asm volatile("s_waitcnt lgkmcnt(0)" ::: "memory")
#define SCHED0() __builtin_amdgcn_sched_barrier(0)
#define GATE2()  asm volatile("s_waitcnt vmcnt(2)" ::: "memory")
#define GATE0()  asm volatile("s_waitcnt vmcnt(0)" ::: "memory")

#define STAGE_A(t_, bo) do { \
  _Pragma("unroll") for (int j_ = 0; j_ < 2; ++j_) \
    g2l16(baseA[j_] + (long)(t_) * 64, sm + (bo) + (w * 2 + j_) * 1024); \
} while (0)

#define LOAD_A(dst, bo) do { \
  _Pragma("unroll") for (int m_ = 0; m_ < 4; ++m_) \
    _Pragma("unroll") for (int h_ = 0; h_ < 2; ++h_) \
      dst[m_][h_] = *(const bf16x8*)(sm + (bo) + aoffbase + m_ * 2048 + swz[h_]); \
} while (0)

#define LOADB(dst, t_) do { \
  const __bf16* p_ = pBw + (size_t)(t_) * 16384; \
  _Pragma("unroll") for (int n_ = 0; n_ < 4; ++n_) \
    _Pragma("unroll") for (int h_ = 0; h_ < 2; ++h_) \
      dst[n_][h_] = *(const bf16x8*)(p_ + (n_ * 2 + h_) * 512); \
} while (0)

#define MMA32(fa_, fb_) do { \
  __builtin_amdgcn_s_setprio(1); \
  _Pragma("unroll") for (int m_ = 0; m_ < 4; ++m_) \
    _Pragma("unroll") for (int n_ = 0; n_ < 4; ++n_) { \
      acc[m_][n_] = __builtin_amdgcn_mfma_f32_16x16x32_bf16( \
          fa_[m_][0], fb_[n_][0], acc[m_][n_], 0, 0, 0); \
      acc[m_][n_] = __builtin_amdgcn_mfma_f32_16x16x32_bf16( \
          fa_[m_][1], fb_[n_][1], acc[m_][n_], 0, 0, 0); \
    } \
  __builtin_amdgcn_s_setprio(0); \
} while (0)

__global__ __launch_bounds__(512, 2)
void gemmB(const __bf16* __restrict__ A, const __bf16* __restrict__ Wp,
           const float* __restrict__ bias, float* __restrict__ out) {
  __shared__ __align__(128) char sm[147456];   // A bufs @0/16K/32K; epilogue reuse
  const int tid = threadIdx.x, lane = tid & 63, w = tid >> 6;
  const int wm = w >> 2, wn = w & 3;           // 2M x 4N waves; wave 64x64

  const int bid = blockIdx.x;
  const int logical = (bid & 7) * 32 + (bid >> 3);  // XCD swizzle (bijective, 256=8x32)
  const int tm = logical & 15;                 // 16 M-tiles (BM=128)
  const int tn = logical >> 4;                 // 16 N-tiles (BN=256)

  // A staging (R5-proven): pre-swizzled granule source, linear LDS dest
  const int rlo = lane >> 3;
  const int gsw = (lane & 7) ^ rlo;
  const __bf16* baseA[2];
#pragma unroll
  for (int j = 0; j < 2; ++j)
    baseA[j] = A + (long)(tm * 128 + w * 16 + j * 8 + rlo) * Kdim + gsw * 8;

  int swz[2];
#pragma unroll
  for (int h = 0; h < 2; ++h)
    swz[h] = (((h * 4 + (lane >> 4)) ^ (lane & 7)) << 4);
  const int aoffbase = (wm * 64 + (lane & 15)) * 128;

  // B per-lane packed base: byte = (tn*2048 + wn*8)*1024 + lane*16
  const __bf16* pBw = Wp + ((size_t)(tn * 2048 + wn * 8) * 512) + lane * 8;

  f32x4 acc[4][4] = {};
  bf16x8 fa[4][2], fbX[4][2], fbY[4][2];

  // prologue: order A0, B0, A1  -> GATE(2) at t=0 retires A0+B0, leaves A1
  STAGE_A(0, 0);
  LOADB(fbX, 0);
  STAGE_A(1, 16384);

  int bo0 = 0, bo1 = 16384, bo2 = 32768;
  for (int i = 0; i < NT / 2; ++i) {
    const int t0 = 2 * i, t1 = 2 * i + 1;
    // ---- tile t0 (buf bo0, B in fbX) ----
    GATE2(); BAR();
    LOAD_A(fa, bo0);
    LOADB(fbY, t1);                       // t1 <= 63 always
    if (t0 + 2 < NT) STAGE_A(t0 + 2, bo2);
    LGKM0(); SCHED0();
    MMA32(fa, fbX);
    // ---- tile t1 (buf bo1, B in fbY) ----
    if (t1 == NT - 1) { GATE0(); } else { GATE2(); }
    BAR();
    LOAD_A(fa, bo1);
    if (t1 + 1 < NT) LOADB(fbX, t1 + 1);
    if (t1 + 2 < NT) STAGE_A(t1 + 2, bo0);
    LGKM0(); SCHED0();
    MMA32(fa, fbY);
    int tmp = bo0; bo0 = bo2; bo2 = bo1; bo1 = tmp;   // (bo0,bo1,bo2) <- (bo2,bo0,bo1)
  }

  // epilogue (R5-proven): acc -> LDS [128][260] f32, coalesced float4 + bias
  float* lf = (float*)sm;
  const int r4 = (lane >> 4) * 4;
  const int cl = lane & 15;
#pragma unroll
  for (int m = 0; m < 4; ++m)
#pragma unroll
    for (int n = 0; n < 4; ++n)
#pragma unroll
      for (int r = 0; r < 4; ++r) {
        int row = wm * 64 + m * 16 + r4 + r;
        int col = wn * 64 + n * 16 + cl;
        lf[row * 260 + col] = acc[m][n][r];
      }
  __syncthreads();
#pragma unroll
  for (int i = 0; i < 16; ++i) {
    int idx = tid + i * 512;
    int row = idx >> 6;
    int c4 = idx & 63;
    f32x4 v = *(const f32x4*)(lf + row * 260 + c4 * 4);
    float4 bv = *(const float4*)(bias + tn * 256 + c4 * 4);
    v[0] += bv.x; v[1] += bv.y; v[2] += bv.z; v[3] += bv.w;
    *(f32x4*)(out + (long)(tm * 128 + row) * Ndim + tn * 256 + c4 * 4) = v;
  }
}

extern "C" void kernel_launch(void* const* d_in, const int* in_sizes, int n_in,
                              void* d_out, int out_size, void* d_ws, size_t ws_size,
                              hipStream_t stream) {
  const float* x      = (const float*)d_in[0];
  const float* binary = (const float*)d_in[1];
  const float* alpha  = (const float*)d_in[2];
  const float* bias   = (const float*)d_in[3];
  float* out = (float*)d_out;

  __bf16* wp = (__bf16*)d_ws;                              // 32 MB packed W
  __bf16* xb = wp + (size_t)Ndim * Kdim;                   // 16 MB X bf16 [M][K]

  prep<<<dim3(WPK_BLOCKS + CVT_BLOCKS), 256, 0, stream>>>(binary, alpha, x, wp, xb);
  gemmB<<<dim3(256), 512, 0, stream>>>(xb, wp, bias, out);
}

// Round 12
// 121.958 us; speedup vs baseline: 1.0999x; 1.0999x over previous
//
#include <hip/hip_runtime.h>
#include <hip/hip_bf16.h>
#include <stdint.h>

typedef __bf16 bf16x8 __attribute__((ext_vector_type(8)));
typedef float  f32x4  __attribute__((ext_vector_type(4)));

static constexpr int Mdim = 2048;   // B*S
static constexpr int Ndim = 4096;   // O
static constexpr int Kdim = 4096;   // I = G*A
static constexpr int DQ_BLOCKS = (Ndim * Kdim / 8) / 256;        // 8192
static constexpr int CVT_BLOCKS = (Mdim * Kdim / 8) / 256;       // 4096

// ---------------- fused prep: dequant W -> bf16 [O][K], cast X -> bf16 [M][K]
__global__ __launch_bounds__(256)
void prep(const float* __restrict__ binary, const float* __restrict__ alpha,
          const float* __restrict__ x, __bf16* __restrict__ w,
          __bf16* __restrict__ xb) {
  const int b = blockIdx.x;
  const int t = threadIdx.x;
  if (b < DQ_BLOCKS) {
    long e = ((long)b * 256 + t) * 8;       // 8 weights/thread
    int o = (int)(e >> 12);
    int g = (int)((e & 4095) >> 7);
    const float* al = alpha + ((long)o * 32 + g) * 3;
    float a0 = al[0], a1 = al[1], a2 = al[2];
    const float4* q = (const float4*)(binary + e * 3);  // 96B contiguous
    float4 q0 = q[0], q1 = q[1], q2 = q[2], q3 = q[3], q4 = q[4], q5 = q[5];
    bf16x8 wv;
    wv[0] = (__bf16)(a0 * q0.x + a1 * q0.y + a2 * q0.z);
    wv[1] = (__bf16)(a0 * q0.w + a1 * q1.x + a2 * q1.y);
    wv[2] = (__bf16)(a0 * q1.z + a1 * q1.w + a2 * q2.x);
    wv[3] = (__bf16)(a0 * q2.y + a1 * q2.z + a2 * q2.w);
    wv[4] = (__bf16)(a0 * q3.x + a1 * q3.y + a2 * q3.z);
    wv[5] = (__bf16)(a0 * q3.w + a1 * q4.x + a2 * q4.y);
    wv[6] = (__bf16)(a0 * q4.z + a1 * q4.w + a2 * q5.x);
    wv[7] = (__bf16)(a0 * q5.y + a1 * q5.z + a2 * q5.w);
    *(bf16x8*)(w + e) = wv;
  } else {
    long e = ((long)(b - DQ_BLOCKS) * 256 + t) * 8;
    float4 v0 = *(const float4*)(x + e);
    float4 v1 = *(const float4*)(x + e + 4);
    bf16x8 r;
    r[0] = (__bf16)v0.x; r[1] = (__bf16)v0.y; r[2] = (__bf16)v0.z; r[3] = (__bf16)v0.w;
    r[4] = (__bf16)v1.x; r[5] = (__bf16)v1.y; r[6] = (__bf16)v1.z; r[7] = (__bf16)v1.w;
    *(bf16x8*)(xb + e) = r;
  }
}

// ---------------- split-K reduce: out = P0 + P1 + bias  (bf16 partials)
__global__ __launch_bounds__(256)
void reduce_add(const __bf16* __restrict__ p, const float* __restrict__ bias,
                float* __restrict__ out) {
  long e = ((long)blockIdx.x * 256 + threadIdx.x) * 8;
  bf16x8 a = *(const bf16x8*)(p + e);
  bf16x8 c = *(const bf16x8*)(p + (long)Mdim * Ndim + e);
  int col = (int)(e & (Ndim - 1));
  float4 bv0 = *(const float4*)(bias + col);
  float4 bv1 = *(const float4*)(bias + col + 4);
  float4 r0, r1;
  r0.x = (float)a[0] + (float)c[0] + bv0.x;
  r0.y = (float)a[1] + (float)c[1] + bv0.y;
  r0.z = (float)a[2] + (float)c[2] + bv0.z;
  r0.w = (float)a[3] + (float)c[3] + bv0.w;
  r1.x = (float)a[4] + (float)c[4] + bv1.x;
  r1.y = (float)a[5] + (float)c[5] + bv1.y;
  r1.z = (float)a[6] + (float)c[6] + bv1.z;
  r1.w = (float)a[7] + (float)c[7] + bv1.w;
  *(float4*)(out + e) = r0;
  *(float4*)(out + e + 4) = r1;
}

// ---------------- 256x256 split-K=2 GEMM, 8 waves (2Mx4N, wave 128x64),
// BK=64, double-buffered LDS (128KB), 8 phases / 2 tiles, GATE(8) steady.
static constexpr int KSLICE = 2048;
static constexpr int NT = KSLICE / 64;   // 32 K-tiles per slice
static constexpr int HB = 65536;         // bytes per buffer (A 32KB + B 32KB)

__device__ __forceinline__ void g2l16(const void* g, void* l) {
  __builtin_amdgcn_global_load_lds(
      (const __attribute__((address_space(1))) void*)g,
      (__attribute__((address_space(3))) void*)l, 16, 0, 0);
}

#define BAR()    __builtin_amdgcn_s_barrier()
#define LGKM0()  asm volatile("s_waitcnt lgkmcnt(0)" ::: "memory")
#define SCHED0() __builtin_amdgcn_sched_barrier(0)
#define GATE8()  asm volatile("s_waitcnt vmcnt(8)" ::: "memory")
#define GATE0()  asm volatile("s_waitcnt vmcnt(0)" ::: "memory")

// Stage units (2 x g2l16 each).  LDS linear dest; source pre-swizzled
// (granule ^= row&7) so read-side XOR matches. [rule 21]
#define STAGE_A1(t, bo) do { \
  g2l16(baseA +                 (long)(t) * 64, sm + (bo) +     0 + w * 1024); \
  g2l16(baseA + 128L * Kdim   + (long)(t) * 64, sm + (bo) + 16384 + w * 1024); \
} while (0)
#define STAGE_A2(t, bo) do { \
  g2l16(baseA +  64L * Kdim   + (long)(t) * 64, sm + (bo) +  8192 + w * 1024); \
  g2l16(baseA + 192L * Kdim   + (long)(t) * 64, sm + (bo) + 24576 + w * 1024); \
} while (0)
#define STAGE_B1(t, bo) do { \
  g2l16(baseB +                 (long)(t) * 64, sm + (bo) + 32768 + bq * 1024); \
  g2l16(baseB +   8L * Kdim   + (long)(t) * 64, sm + (bo) + 32768 + bq * 1024 + 1024); \
} while (0)
#define STAGE_B2(t, bo) do { \
  g2l16(baseB +  32L * Kdim   + (long)(t) * 64, sm + (bo) + 32768 + bq * 1024 + 4096); \
  g2l16(baseB +  40L * Kdim   + (long)(t) * 64, sm + (bo) + 32768 + bq * 1024 + 5120); \
} while (0)

#define LOAD_A4(dst, bo, m0_) do { \
  _Pragma("unroll") for (int m_ = 0; m_ < 4; ++m_) \
    _Pragma("unroll") for (int h_ = 0; h_ < 2; ++h_) \
      dst[m_][h_] = *(const bf16x8*)(sm + (bo) + aoffbase + ((m0_) + m_) * 2048 + swz[h_]); \
} while (0)
#define LOAD_B2(dst, bo, n0_) do { \
  _Pragma("unroll") for (int n_ = 0; n_ < 2; ++n_) \
    _Pragma("unroll") for (int h_ = 0; h_ < 2; ++h_) \
      dst[n_][h_] = *(const bf16x8*)(sm + (bo) + boffbase + ((n0_) + n_) * 2048 + swz[h_]); \
} while (0)

#define MMA8(fa_, fb_, m0_, n0_) do { \
  __builtin_amdgcn_s_setprio(1); \
  _Pragma("unroll") for (int m_ = 0; m_ < 4; ++m_) \
    _Pragma("unroll") for (int n_ = 0; n_ < 2; ++n_) { \
      acc[(m0_) + m_][(n0_) + n_] = __builtin_amdgcn_mfma_f32_16x16x32_bf16( \
          fa_[m_][0], fb_[n_][0], acc[(m0_) + m_][(n0_) + n_], 0, 0, 0); \
      acc[(m0_) + m_][(n0_) + n_] = __builtin_amdgcn_mfma_f32_16x16x32_bf16( \
          fa_[m_][1], fb_[n_][1], acc[(m0_) + m_][(n0_) + n_], 0, 0, 0); \
    } \
  __builtin_amdgcn_s_setprio(0); \
} while (0)

#define KTILE(t_, bo, PF_, LASTGATE) do { \
  /* P1 */ \
  LOAD_A4(fa, bo, 0); LOAD_B2(fb01, bo, 0); \
  BAR(); LGKM0(); SCHED0(); \
  MMA8(fa, fb01, 0, 0); \
  BAR(); \
  /* P2 */ \
  LOAD_B2(fb23, bo, 2); \
  if (PF_) { STAGE_A1((t_) + 2, bo); STAGE_B1((t_) + 2, bo); } \
  BAR(); LGKM0(); SCHED0(); \
  MMA8(fa, fb23, 0, 2); \
  BAR(); \
  /* P3 */ \
  LOAD_A4(fa, bo, 4); \
  if (PF_) STAGE_B2((t_) + 2, bo); \
  BAR(); LGKM0(); SCHED0(); \
  MMA8(fa, fb01, 4, 0); \
  BAR(); \
  /* P4 */ \
  if (PF_) { STAGE_A2((t_) + 2, bo); GATE8(); } else { LASTGATE; } \
  BAR(); \
  MMA8(fa, fb23, 4, 2); \
  BAR(); \
} while (0)

__global__ __launch_bounds__(512, 2)
void gemm256(const __bf16* __restrict__ A, const __bf16* __restrict__ Bw,
             __bf16* __restrict__ P) {
  __shared__ __align__(128) char sm[2 * HB];   // 128 KB
  const int tid = threadIdx.x, lane = tid & 63, w = tid >> 6;
  const int wm = w >> 2, wn = w & 3;           // wave tile 128x64

  const int bid = blockIdx.x;
  const int logical = (bid & 7) * 32 + (bid >> 3);
  const int ks = logical >> 7;                 // split-K slice
  const int tile = logical & 127;
  const int tm = tile & 7, tn = tile >> 3;     // 8 x 16 tiles of 256x256
  const int kbase = ks * KSLICE;

  __bf16* Pout = P + (long)ks * Mdim * Ndim;

  const int rlo = lane >> 3;
  const int gsw = (lane & 7) ^ rlo;
  const __bf16* baseA = A + (long)(tm * 256 + w * 8 + rlo) * Kdim + kbase + gsw * 8;
  const __bf16* baseB = Bw + (long)(tn * 256 + (w >> 1) * 64 + (w & 1) * 16 + rlo) * Kdim
                        + kbase + gsw * 8;
  const int bq = (w >> 1) * 8 + (w & 1) * 2;

  int swz[2];
#pragma unroll
  for (int h = 0; h < 2; ++h)
    swz[h] = (((h * 4 + (lane >> 4)) ^ (lane & 7)) << 4);
  const int aoffbase = (wm * 128 + (lane & 15)) * 128;
  const int boffbase = 32768 + (wn * 64 + (lane & 15)) * 128;

  f32x4 acc[8][4] = {};
  bf16x8 fa[4][2], fb01[2][2], fb23[2][2];

  STAGE_A1(0, 0);  STAGE_B1(0, 0);  STAGE_B2(0, 0);  STAGE_A2(0, 0);
  STAGE_A1(1, HB); STAGE_B1(1, HB); STAGE_B2(1, HB); STAGE_A2(1, HB);
  GATE8();
  BAR();

  for (int i = 0; i < NT / 2; ++i) {
    const int t0 = 2 * i, t1 = 2 * i + 1;
    const bool pf = (i < NT / 2 - 1);
    KTILE(t0, 0,  pf, GATE0());
    KTILE(t1, HB, pf, GATE0());
  }

  // ---- epilogue: coalesced bf16 partial stores via LDS transpose ----
  // 4 chunks of 64 rows; LDS [64][264] bf16 (pad 8 -> write rows spread banks).
  __bf16* lb = (__bf16*)sm;
  const int r4 = (lane >> 4) * 4;
  const int cl = lane & 15;
  for (int c = 0; c < 4; ++c) {
    if (wm == (c >> 1)) {
      const int mlo = (c & 1) * 4;
#pragma unroll
      for (int mm = 0; mm < 4; ++mm)
#pragma unroll
        for (int n = 0; n < 4; ++n)
#pragma unroll
          for (int r = 0; r < 4; ++r) {
            int rowc = mm * 16 + r4 + r;          // 0..63
            int col = wn * 64 + n * 16 + cl;
            lb[rowc * 264 + col] = (__bf16)acc[mlo + mm][n][r];
          }
    }
    __syncthreads();
#pragma unroll
    for (int i2 = 0; i2 < 4; ++i2) {
      int idx = tid + i2 * 512;                   // 2048 bf16x8 units
      int rowc = idx >> 5;                        // 32 units per 256-col row
      int u = idx & 31;
      bf16x8 v = *(const bf16x8*)(lb + rowc * 264 + u * 8);
      *(bf16x8*)(Pout + (long)(tm * 256 + c * 64 + rowc) * Ndim + tn * 256 + u * 8) = v;
    }
    __syncthreads();
  }
}

extern "C" void kernel_launch(void* const* d_in, const int* in_sizes, int n_in,
                              void* d_out, int out_size, void* d_ws, size_t ws_size,
                              hipStream_t stream) {
  const float* x      = (const float*)d_in[0];
  const float* binary = (const float*)d_in[1];
  const float* alpha  = (const float*)d_in[2];
  const float* bias   = (const float*)d_in[3];
  float* out = (float*)d_out;

  __bf16* wb = (__bf16*)d_ws;                              // 32 MB  W bf16 [N][K]
  __bf16* xb = wb + (size_t)Ndim * Kdim;                   // 16 MB  X bf16 [M][K]
  __bf16* pp = xb + (size_t)Mdim * Kdim;                   // 32 MB  partials bf16 [2][M][N]

  prep<<<dim3(DQ_BLOCKS + CVT_BLOCKS), 256, 0, stream>>>(binary, alpha, x, wb, xb);
  gemm256<<<dim3(256), 512, 0, stream>>>(xb, wb, pp);
  reduce_add<<<dim3(Mdim * Ndim / 8 / 256), 256, 0, stream>>>(pp, bias, out);
}